// Round 5
// baseline (163.935 us; speedup 1.0000x reference)
//
#include <hip/hip_runtime.h>
#include <stdint.h>

typedef unsigned short u16;

#define L_SEQ 2048
#define DMODEL 1024
#define NHEAD 16

using f32x4 = __attribute__((ext_vector_type(4))) float;
using s16x8 = __attribute__((ext_vector_type(8))) short;

__device__ __forceinline__ u16 f2b(float f) {
    union { float f; uint32_t u; } v; v.f = f;
    uint32_t r = v.u + 0x7fffu + ((v.u >> 16) & 1u);
    return (u16)(r >> 16);
}

__device__ __forceinline__ void gld16(const void* g, void* l) {
    __builtin_amdgcn_global_load_lds(
        (__attribute__((address_space(1))) void*)(uintptr_t)g,
        (__attribute__((address_space(3))) void*)(uintptr_t)l,
        16, 0, 0);
}

// ---------------- fused f32 -> bf16 convert (x + 4 weights, one launch) ----------------
__global__ __launch_bounds__(256)
void k_tobf16_all(const float* __restrict__ x, const float* __restrict__ wq,
                  const float* __restrict__ wk, const float* __restrict__ wv,
                  const float* __restrict__ wo,
                  u16* __restrict__ xb, u16* __restrict__ wqb, u16* __restrict__ wkb,
                  u16* __restrict__ wvb, u16* __restrict__ wob) {
    const int NX = L_SEQ * DMODEL / 8;     // 262144
    const int NW = DMODEL * DMODEL / 8;    // 131072 = 2^17
    int i = blockIdx.x * blockDim.x + threadIdx.x;
    const float* src; u16* dst; int j;
    if (i < NX) { src = x; dst = xb; j = i; }
    else {
        int t = i - NX; int sel = t >> 17; j = t & (NW - 1);
        src = (sel == 0) ? wq : (sel == 1) ? wk : (sel == 2) ? wv : wo;
        dst = (sel == 0) ? wqb : (sel == 1) ? wkb : (sel == 2) ? wvb : wob;
    }
    const float4* s4 = (const float4*)src;
    float4 a = s4[2 * j], b = s4[2 * j + 1];
    union { s16x8 v; u16 u[8]; } o;
    o.u[0] = f2b(a.x); o.u[1] = f2b(a.y); o.u[2] = f2b(a.z); o.u[3] = f2b(a.w);
    o.u[4] = f2b(b.x); o.u[5] = f2b(b.y); o.u[6] = f2b(b.z); o.u[7] = f2b(b.w);
    ((s16x8*)dst)[j] = o.v;
}

// ---------------- phase features -> packed (c,s) float2 ----------------
__global__ __launch_bounds__(256)
void k_phase(const float* __restrict__ x, const float* __restrict__ Wp,
             const float* __restrict__ bp, float2* __restrict__ CSph) {
    const int tid = threadIdx.x;
    const int w = tid >> 6, lane = tid & 63;
    const int m = blockIdx.x * 4 + w;
    __shared__ float pbuf[4][32];
    float xr[16];
#pragma unroll
    for (int i = 0; i < 16; ++i) xr[i] = x[(size_t)m * DMODEL + lane + 64 * i];
#pragma unroll 4
    for (int n = 0; n < 32; ++n) {
        const float* wrow = Wp + n * DMODEL;
        float s = 0.f;
#pragma unroll
        for (int i = 0; i < 16; ++i) s += xr[i] * wrow[lane + 64 * i];
#pragma unroll
        for (int msk = 32; msk >= 1; msk >>= 1) s += __shfl_xor(s, msk);
        if (lane == 0) pbuf[w][n] = s + bp[n];
    }
    __syncthreads();
    if (lane < 16) {
        float c = pbuf[w][2 * lane], sn = pbuf[w][2 * lane + 1];
        float nrm = sqrtf(c * c + sn * sn);
        float inv = 1.0f / fmaxf(nrm, 1e-6f);
        CSph[(size_t)lane * L_SEQ + m] = make_float2(c * inv, sn * inv);
    }
}

// ---------------- bf16 B^T GEMM (m97 structure, verified R1 — unchanged) ----------------
template <int OUTF32>
__global__ __launch_bounds__(256, 2)
void k_gemm_bt(const u16* __restrict__ A,
               const u16* __restrict__ B0, const u16* __restrict__ B1, const u16* __restrict__ B2,
               const float* __restrict__ c0, const float* __restrict__ c1, const float* __restrict__ c2,
               void* __restrict__ Out, int ldo, int K) {
    __shared__ u16 As[128 * 64];
    __shared__ u16 Bs[128 * 64];
    const int tid = threadIdx.x;
    const int w = tid >> 6, lane = tid & 63;
    const int wr = w >> 1, wc = w & 1;
    const int u = lane & 15, g = lane >> 4;
    const int mt = blockIdx.x, nt = blockIdx.y;
    const int seg = nt >> 3, ntl = nt & 7;
    const u16* Bp = (seg == 0) ? B0 : (seg == 1) ? B1 : B2;
    const float* biasp = (seg == 0) ? c0 : (seg == 1) ? c1 : c2;

    const u16* Ab = A + (size_t)(mt * 128 + w * 32) * K;
    const u16* Bb = Bp + (size_t)(ntl * 128 + w * 32) * K;
    const int lr = lane >> 3;
    const int lc = (lane & 7) * 8;

    f32x4 acc[4][4] = {};

    for (int k0 = 0; k0 < K; k0 += 64) {
#pragma unroll
        for (int c = 0; c < 4; ++c)
            gld16(Ab + (size_t)(c * 8 + lr) * K + k0 + lc, &As[(w * 32 + c * 8) * 64]);
#pragma unroll
        for (int c = 0; c < 4; ++c)
            gld16(Bb + (size_t)(c * 8 + lr) * K + k0 + lc, &Bs[(w * 32 + c * 8) * 64]);
        __syncthreads();
#pragma unroll
        for (int ks = 0; ks < 2; ++ks) {
            s16x8 af[4], bf[4];
#pragma unroll
            for (int i = 0; i < 4; ++i)
                af[i] = *(const s16x8*)&As[(wr * 64 + i * 16 + u) * 64 + ks * 32 + g * 8];
#pragma unroll
            for (int j = 0; j < 4; ++j)
                bf[j] = *(const s16x8*)&Bs[(wc * 64 + j * 16 + u) * 64 + ks * 32 + g * 8];
#pragma unroll
            for (int i = 0; i < 4; ++i)
#pragma unroll
                for (int j = 0; j < 4; ++j)
                    acc[i][j] = __builtin_amdgcn_mfma_f32_16x16x32_bf16(af[i], bf[j], acc[i][j], 0, 0, 0);
        }
        __syncthreads();
    }

#pragma unroll
    for (int i = 0; i < 4; ++i) {
#pragma unroll
        for (int j = 0; j < 4; ++j) {
            const int row0 = mt * 128 + wr * 64 + i * 16 + g * 4;
            const int col = nt * 128 + wc * 64 + j * 16 + u;
            const int colseg = ntl * 128 + wc * 64 + j * 16 + u;
            const float bias = biasp[colseg];
#pragma unroll
            for (int r = 0; r < 4; ++r) {
                float val = acc[i][j][r] + bias;
                if (OUTF32)
                    ((float*)Out)[(size_t)(row0 + r) * ldo + col] = val;
                else
                    ((u16*)Out)[(size_t)(row0 + r) * ldo + col] = f2b(val);
            }
        }
    }
}

// ---------------- V transpose: qkv V section [token][feat] -> VtG [feat][token] ----------------
__global__ __launch_bounds__(256)
void k_transposeV(const u16* __restrict__ qkv, u16* __restrict__ VtG) {
    __shared__ u16 T[64 * 64];   // byte(r,c) = r*128 + ((c*2) ^ ((((r>>3)^r)&7)<<4))
    const int tb = blockIdx.x;   // token block (64 tokens)
    const int fb = blockIdx.y;   // feature block (64 feats)
    const int tid = threadIdx.x;
    char* Tb = (char*)T;
#pragma unroll
    for (int t = 0; t < 2; ++t) {
        int ci = t * 256 + tid;
        int r = ci >> 3, cb = ci & 7;
        s16x8 v = *(const s16x8*)(qkv + (size_t)(tb * 64 + r) * (3 * DMODEL) + 2 * DMODEL + fb * 64 + cb * 8);
        int kk = (((r >> 3) ^ r) & 7) << 4;
        *(s16x8*)(Tb + r * 128 + ((cb * 16) ^ kk)) = v;
    }
    __syncthreads();
#pragma unroll
    for (int t = 0; t < 2; ++t) {
        int co = t * 256 + tid;
        int f = co >> 3, t8 = co & 7;
        union { u16 us[8]; s16x8 v; } o;
#pragma unroll
        for (int x = 0; x < 8; ++x) {
            int r = t8 * 8 + x;
            int kk = (((r >> 3) ^ r) & 7) << 4;
            o.us[x] = *(const u16*)(Tb + r * 128 + ((f * 2) ^ kk));
        }
        *(s16x8*)(VtG + (size_t)(fb * 64 + f) * L_SEQ + tb * 64 + t8 * 8) = o.v;
    }
}

// ---------------- fused attention v4: intra-block split-K ----------------
// grid (L/64, H), 512 threads = 8 waves. Waves 0-3: keys [0,64) of each
// 128-key tile; waves 4-7: keys [64,128). Same 64 q-rows. Private (m,l,O)
// per half, flash-merged in LDS at the end. K staged via gld16 (swizzled,
// double-buffered); V fragments loaded straight from VtG into registers.
__global__ __launch_bounds__(512, 4)
void k_attn(const u16* __restrict__ QKV, const u16* __restrict__ VtG,
            const float2* __restrict__ CSph,
            const float* __restrict__ gamma, u16* __restrict__ Oout) {
    const int h = blockIdx.y;
    const int qb = blockIdx.x * 64;
    const int tid = threadIdx.x;
    const int w = tid >> 6, lane = tid & 63;
    const int u = lane & 15, g = lane >> 4;
    const int wq = w & 3;            // q sub-block
    const int kh = (w >> 2) << 6;    // key-half offset: 0 or 64
    const int ld = 3 * DMODEL;
    const int NT = L_SEQ / 128;      // 16
    const int KBUF = 128 * 64 * 2;   // 16 KB per K buffer

    // Ks: byte(row,d) = row*128 + ((d*2) ^ ((row&7)<<4)), row = key in [0,128)
    // Pl (per wave): byte(q,kk) = q*128 + ((kk*2) ^ ((q&7)<<4)), kk in [0,64)
    __shared__ __attribute__((aligned(16))) char smem[2 * 16384 + 8 * 2048];
    char* ksBase = smem;
    char* PlB = smem + 32768 + w * 2048;

    const float LOG2E = 1.44269504088896f;
    const float gate2 = (0.08f / (1.0f + __expf(-gamma[h]))) * LOG2E;
    const float SC2 = 0.125f * LOG2E;

    const u16* Qp = QKV + h * 64;
    const u16* Kp = QKV + DMODEL + h * 64;
    const u16* VtH = VtG + (size_t)h * 64 * L_SEQ;
    const float2* CS = CSph + (size_t)h * L_SEQ;

    s16x8 aq0, aq1;
    {
        const int qrow = qb + wq * 16 + u;
        aq0 = *(const s16x8*)(Qp + (size_t)qrow * ld + g * 8);
        aq1 = *(const s16x8*)(Qp + (size_t)qrow * ld + 32 + g * 8);
    }
    float gcq[4], gsq[4];
#pragma unroll
    for (int r = 0; r < 4; ++r) {
        float2 cs = CS[qb + wq * 16 + g * 4 + r];
        gcq[r] = gate2 * cs.x;
        gsq[r] = gate2 * cs.y;
    }

    // K staging: 16 KB tile = 1024 chunks of 16B; 512 threads x 2 chunks.
    unsigned dstK[2]; size_t srcK[2];
#pragma unroll
    for (int t = 0; t < 2; ++t) {
        int ci = t * 512 + w * 64 + lane;
        int rK = ci >> 3, cK = ci & 7;
        dstK[t] = (unsigned)(t * 8192 + w * 1024);   // wave-uniform; HW adds lane*16
        srcK[t] = (size_t)rK * ld + (size_t)((cK ^ (rK & 7)) * 8);
    }

#pragma unroll
    for (int t = 0; t < 2; ++t)
        gld16(Kp + srcK[t], ksBase + dstK[t]);
    __syncthreads();

    float mrow[4], lrow[4];
    f32x4 oacc[4] = {};
#pragma unroll
    for (int r = 0; r < 4; ++r) { mrow[r] = -1e30f; lrow[r] = 0.f; }

    for (int kt = 0; kt < NT; ++kt) {
        const int cur = kt & 1;
        const char* kCur = ksBase + cur * 16384;
        const int k0 = kt * 128 + kh;

        // V fragments straight from global V^T (issued early; used in PV)
        s16x8 vbr[4][2];
#pragma unroll
        for (int db = 0; db < 4; ++db)
#pragma unroll
            for (int ks = 0; ks < 2; ++ks)
                vbr[db][ks] = *(const s16x8*)(VtH + (size_t)(db * 16 + u) * L_SEQ + k0 + ks * 32 + g * 8);

        if (kt + 1 < NT) {
            const u16* Kn = Kp + (size_t)(kt + 1) * 128 * ld;
            char* kN = ksBase + (cur ^ 1) * 16384;
#pragma unroll
            for (int t = 0; t < 2; ++t)
                gld16(Kn + srcK[t], kN + dstK[t]);
        }

        // ---- S = Q K^T (16q x 64k per wave) ----
        f32x4 sf[4] = {};
        const int x0 = (g * 16) ^ ((u & 7) << 4);
#pragma unroll
        for (int kb = 0; kb < 4; ++kb) {
            const int rowb = (kh + kb * 16 + u) * 128;
            s16x8 b0 = *(const s16x8*)(kCur + rowb + x0);
            s16x8 b1 = *(const s16x8*)(kCur + rowb + (x0 ^ 64));
            sf[kb] = __builtin_amdgcn_mfma_f32_16x16x32_bf16(aq0, b0, sf[kb], 0, 0, 0);
            sf[kb] = __builtin_amdgcn_mfma_f32_16x16x32_bf16(aq1, b1, sf[kb], 0, 0, 0);
        }

        // ---- bias + online softmax (log2 domain) ----
        float ck4[4], sk4[4];
#pragma unroll
        for (int kb = 0; kb < 4; ++kb) {
            float2 cs = CS[k0 + kb * 16 + u];
            ck4[kb] = cs.x; sk4[kb] = cs.y;
        }
        float sv[4][4], tmax[4];
#pragma unroll
        for (int r = 0; r < 4; ++r) tmax[r] = -1e30f;
#pragma unroll
        for (int kb = 0; kb < 4; ++kb)
#pragma unroll
            for (int r = 0; r < 4; ++r) {
                float xv = sf[kb][r] * SC2 + gcq[r] * ck4[kb] + gsq[r] * sk4[kb];
                sv[kb][r] = xv;
                tmax[r] = fmaxf(tmax[r], xv);
            }
#pragma unroll
        for (int r = 0; r < 4; ++r) {
#pragma unroll
            for (int msk = 1; msk <= 8; msk <<= 1)
                tmax[r] = fmaxf(tmax[r], __shfl_xor(tmax[r], msk));
        }
        float scl[4], tsum[4];
#pragma unroll
        for (int r = 0; r < 4; ++r) {
            float mn = fmaxf(mrow[r], tmax[r]);
            scl[r] = __builtin_amdgcn_exp2f(mrow[r] - mn);
            mrow[r] = mn;
            tsum[r] = 0.f;
        }
#pragma unroll
        for (int kb = 0; kb < 4; ++kb)
#pragma unroll
            for (int r = 0; r < 4; ++r) {
                float p = __builtin_amdgcn_exp2f(sv[kb][r] - mrow[r]);
                tsum[r] += p;
                int prow = g * 4 + r;
                int pb = prow * 128 + (kb * 16 + u) * 2;
                pb ^= (prow & 7) << 4;
                *(u16*)(PlB + pb) = f2b(p);
            }
#pragma unroll
        for (int r = 0; r < 4; ++r) {
#pragma unroll
            for (int msk = 1; msk <= 8; msk <<= 1)
                tsum[r] += __shfl_xor(tsum[r], msk);
            lrow[r] = lrow[r] * scl[r] + tsum[r];
        }
#pragma unroll
        for (int db = 0; db < 4; ++db)
#pragma unroll
            for (int r = 0; r < 4; ++r)
                oacc[db][r] *= scl[r];

        // ---- O += P V ----
#pragma unroll
        for (int ks = 0; ks < 2; ++ks) {
            s16x8 pa = *(const s16x8*)(PlB + u * 128 + ((ks * 64 + g * 16) ^ ((u & 7) << 4)));
#pragma unroll
            for (int db = 0; db < 4; ++db)
                oacc[db] = __builtin_amdgcn_mfma_f32_16x16x32_bf16(pa, vbr[db][ks], oacc[db], 0, 0, 0);
        }
        __syncthreads();
    }

    // ---- merge key-halves (flash combine), reusing Ks area ----
    float* obuf = (float*)ksBase;                   // [64][64] f32 = 16 KB
    float* mbuf = (float*)(ksBase + 16384);         // [64]
    float* lbuf = (float*)(ksBase + 16384 + 256);   // [64]
    if (w >= 4) {
#pragma unroll
        for (int db = 0; db < 4; ++db)
#pragma unroll
            for (int r = 0; r < 4; ++r)
                obuf[(wq * 16 + g * 4 + r) * 64 + db * 16 + u] = oacc[db][r];
        if (u == 0) {
#pragma unroll
            for (int r = 0; r < 4; ++r) {
                mbuf[wq * 16 + g * 4 + r] = mrow[r];
                lbuf[wq * 16 + g * 4 + r] = lrow[r];
            }
        }
    }
    __syncthreads();
    if (w < 4) {
        float a1[4], a2[4], inv[4];
#pragma unroll
        for (int r = 0; r < 4; ++r) {
            int row16 = w * 16 + g * 4 + r;
            float m2 = mbuf[row16], l2 = lbuf[row16];
            float M = fmaxf(mrow[r], m2);
            a1[r] = __builtin_amdgcn_exp2f(mrow[r] - M);
            a2[r] = __builtin_amdgcn_exp2f(m2 - M);
            inv[r] = 1.0f / (lrow[r] * a1[r] + l2 * a2[r]);
        }
#pragma unroll
        for (int db = 0; db < 4; ++db)
#pragma unroll
            for (int r = 0; r < 4; ++r) {
                float o2 = obuf[(w * 16 + g * 4 + r) * 64 + db * 16 + u];
                float val = (oacc[db][r] * a1[r] + o2 * a2[r]) * inv[r];
                int qr = qb + w * 16 + g * 4 + r;
                Oout[(size_t)qr * DMODEL + h * 64 + db * 16 + u] = f2b(val);
            }
    }
    (void)KBUF;
}

extern "C" void kernel_launch(void* const* d_in, const int* in_sizes, int n_in,
                              void* d_out, int out_size, void* d_ws, size_t ws_size,
                              hipStream_t stream) {
    const float* x  = (const float*)d_in[0];
    const float* Wq = (const float*)d_in[1];
    const float* bq = (const float*)d_in[2];
    const float* Wk = (const float*)d_in[3];
    const float* bk = (const float*)d_in[4];
    const float* Wv = (const float*)d_in[5];
    const float* bv = (const float*)d_in[6];
    const float* Wo = (const float*)d_in[7];
    const float* bo = (const float*)d_in[8];
    const float* Wp = (const float*)d_in[9];
    const float* bp = (const float*)d_in[10];
    const float* gamma = (const float*)d_in[11];
    float* out = (float*)d_out;

    char* ws = (char*)d_ws;
    u16* xb = (u16*)ws;   ws += (size_t)L_SEQ * DMODEL * 2;
    u16* wqb = (u16*)ws;  ws += (size_t)DMODEL * DMODEL * 2;
    u16* wkb = (u16*)ws;  ws += (size_t)DMODEL * DMODEL * 2;
    u16* wvb = (u16*)ws;  ws += (size_t)DMODEL * DMODEL * 2;
    u16* wob = (u16*)ws;  ws += (size_t)DMODEL * DMODEL * 2;
    u16* qkv = (u16*)ws;  ws += (size_t)L_SEQ * 3 * DMODEL * 2;
    u16* attnb = (u16*)ws; ws += (size_t)L_SEQ * DMODEL * 2;
    u16* VtG = (u16*)ws;  ws += (size_t)DMODEL * L_SEQ * 2;
    float2* CSph = (float2*)ws; ws += (size_t)NHEAD * L_SEQ * 8;

    const int ntot8 = (L_SEQ * DMODEL + 4 * DMODEL * DMODEL) / 8;  // 786432
    k_tobf16_all<<<ntot8 / 256, 256, 0, stream>>>(x, Wq, Wk, Wv, Wo, xb, wqb, wkb, wvb, wob);

    k_phase<<<L_SEQ / 4, 256, 0, stream>>>(x, Wp, bp, CSph);

    // fused QKV projection -> qkv [2048, 3072] bf16
    k_gemm_bt<0><<<dim3(16, 24), 256, 0, stream>>>(xb, wqb, wkb, wvb, bq, bk, bv,
                                                   (void*)qkv, 3 * DMODEL, DMODEL);

    // V^T [1024, 2048] bf16
    k_transposeV<<<dim3(L_SEQ / 64, DMODEL / 64), 256, 0, stream>>>(qkv, VtG);

    k_attn<<<dim3(L_SEQ / 64, NHEAD), 512, 0, stream>>>(qkv, VtG, CSph, gamma, attnb);

    // output projection -> d_out f32 [2048, 1024]
    k_gemm_bt<1><<<dim3(16, 8), 256, 0, stream>>>(attnb, wob, wob, wob, bo, bo, bo,
                                                  (void*)out, DMODEL, DMODEL);
}

// Round 6
// 130.681 us; speedup vs baseline: 1.2545x; 1.2545x over previous
//
#include <hip/hip_runtime.h>
#include <stdint.h>

typedef unsigned short u16;

#define L_SEQ 2048
#define DMODEL 1024
#define NHEAD 16

using f32x4 = __attribute__((ext_vector_type(4))) float;
using s16x8 = __attribute__((ext_vector_type(8))) short;

__device__ __forceinline__ u16 f2b(float f) {
    union { float f; uint32_t u; } v; v.f = f;
    uint32_t r = v.u + 0x7fffu + ((v.u >> 16) & 1u);
    return (u16)(r >> 16);
}

__device__ __forceinline__ void gld16(const void* g, void* l) {
    __builtin_amdgcn_global_load_lds(
        (__attribute__((address_space(1))) void*)(uintptr_t)g,
        (__attribute__((address_space(3))) void*)(uintptr_t)l,
        16, 0, 0);
}

// ---------------- fused f32 -> bf16 convert (x + 4 weights, one launch) ----------------
__global__ __launch_bounds__(256)
void k_tobf16_all(const float* __restrict__ x, const float* __restrict__ wq,
                  const float* __restrict__ wk, const float* __restrict__ wv,
                  const float* __restrict__ wo,
                  u16* __restrict__ xb, u16* __restrict__ wqb, u16* __restrict__ wkb,
                  u16* __restrict__ wvb, u16* __restrict__ wob) {
    const int NX = L_SEQ * DMODEL / 8;     // 262144
    const int NW = DMODEL * DMODEL / 8;    // 131072 = 2^17
    int i = blockIdx.x * blockDim.x + threadIdx.x;
    const float* src; u16* dst; int j;
    if (i < NX) { src = x; dst = xb; j = i; }
    else {
        int t = i - NX; int sel = t >> 17; j = t & (NW - 1);
        src = (sel == 0) ? wq : (sel == 1) ? wk : (sel == 2) ? wv : wo;
        dst = (sel == 0) ? wqb : (sel == 1) ? wkb : (sel == 2) ? wvb : wob;
    }
    const float4* s4 = (const float4*)src;
    float4 a = s4[2 * j], b = s4[2 * j + 1];
    union { s16x8 v; u16 u[8]; } o;
    o.u[0] = f2b(a.x); o.u[1] = f2b(a.y); o.u[2] = f2b(a.z); o.u[3] = f2b(a.w);
    o.u[4] = f2b(b.x); o.u[5] = f2b(b.y); o.u[6] = f2b(b.z); o.u[7] = f2b(b.w);
    ((s16x8*)dst)[j] = o.v;
}

// ---------------- phase features -> packed (c,s) float2 ----------------
__global__ __launch_bounds__(256)
void k_phase(const float* __restrict__ x, const float* __restrict__ Wp,
             const float* __restrict__ bp, float2* __restrict__ CSph) {
    const int tid = threadIdx.x;
    const int w = tid >> 6, lane = tid & 63;
    const int m = blockIdx.x * 4 + w;
    __shared__ float pbuf[4][32];
    float xr[16];
#pragma unroll
    for (int i = 0; i < 16; ++i) xr[i] = x[(size_t)m * DMODEL + lane + 64 * i];
#pragma unroll 4
    for (int n = 0; n < 32; ++n) {
        const float* wrow = Wp + n * DMODEL;
        float s = 0.f;
#pragma unroll
        for (int i = 0; i < 16; ++i) s += xr[i] * wrow[lane + 64 * i];
#pragma unroll
        for (int msk = 32; msk >= 1; msk >>= 1) s += __shfl_xor(s, msk);
        if (lane == 0) pbuf[w][n] = s + bp[n];
    }
    __syncthreads();
    if (lane < 16) {
        float c = pbuf[w][2 * lane], sn = pbuf[w][2 * lane + 1];
        float nrm = sqrtf(c * c + sn * sn);
        float inv = 1.0f / fmaxf(nrm, 1e-6f);
        CSph[(size_t)lane * L_SEQ + m] = make_float2(c * inv, sn * inv);
    }
}

// ---------------- bf16 B^T GEMM (m97 structure, verified R1 — unchanged) ----------------
template <int OUTF32>
__global__ __launch_bounds__(256, 2)
void k_gemm_bt(const u16* __restrict__ A,
               const u16* __restrict__ B0, const u16* __restrict__ B1, const u16* __restrict__ B2,
               const float* __restrict__ c0, const float* __restrict__ c1, const float* __restrict__ c2,
               void* __restrict__ Out, int ldo, int K) {
    __shared__ u16 As[128 * 64];
    __shared__ u16 Bs[128 * 64];
    const int tid = threadIdx.x;
    const int w = tid >> 6, lane = tid & 63;
    const int wr = w >> 1, wc = w & 1;
    const int u = lane & 15, g = lane >> 4;
    const int mt = blockIdx.x, nt = blockIdx.y;
    const int seg = nt >> 3, ntl = nt & 7;
    const u16* Bp = (seg == 0) ? B0 : (seg == 1) ? B1 : B2;
    const float* biasp = (seg == 0) ? c0 : (seg == 1) ? c1 : c2;

    const u16* Ab = A + (size_t)(mt * 128 + w * 32) * K;
    const u16* Bb = Bp + (size_t)(ntl * 128 + w * 32) * K;
    const int lr = lane >> 3;
    const int lc = (lane & 7) * 8;

    f32x4 acc[4][4] = {};

    for (int k0 = 0; k0 < K; k0 += 64) {
#pragma unroll
        for (int c = 0; c < 4; ++c)
            gld16(Ab + (size_t)(c * 8 + lr) * K + k0 + lc, &As[(w * 32 + c * 8) * 64]);
#pragma unroll
        for (int c = 0; c < 4; ++c)
            gld16(Bb + (size_t)(c * 8 + lr) * K + k0 + lc, &Bs[(w * 32 + c * 8) * 64]);
        __syncthreads();
#pragma unroll
        for (int ks = 0; ks < 2; ++ks) {
            s16x8 af[4], bf[4];
#pragma unroll
            for (int i = 0; i < 4; ++i)
                af[i] = *(const s16x8*)&As[(wr * 64 + i * 16 + u) * 64 + ks * 32 + g * 8];
#pragma unroll
            for (int j = 0; j < 4; ++j)
                bf[j] = *(const s16x8*)&Bs[(wc * 64 + j * 16 + u) * 64 + ks * 32 + g * 8];
#pragma unroll
            for (int i = 0; i < 4; ++i)
#pragma unroll
                for (int j = 0; j < 4; ++j)
                    acc[i][j] = __builtin_amdgcn_mfma_f32_16x16x32_bf16(af[i], bf[j], acc[i][j], 0, 0, 0);
        }
        __syncthreads();
    }

#pragma unroll
    for (int i = 0; i < 4; ++i) {
#pragma unroll
        for (int j = 0; j < 4; ++j) {
            const int row0 = mt * 128 + wr * 64 + i * 16 + g * 4;
            const int col = nt * 128 + wc * 64 + j * 16 + u;
            const int colseg = ntl * 128 + wc * 64 + j * 16 + u;
            const float bias = biasp[colseg];
#pragma unroll
            for (int r = 0; r < 4; ++r) {
                float val = acc[i][j][r] + bias;
                if (OUTF32)
                    ((float*)Out)[(size_t)(row0 + r) * ldo + col] = val;
                else
                    ((u16*)Out)[(size_t)(row0 + r) * ldo + col] = f2b(val);
            }
        }
    }
}

// ---------------- V transpose: qkv V section [token][feat] -> VtG [feat][token] ----------------
__global__ __launch_bounds__(256)
void k_transposeV(const u16* __restrict__ qkv, u16* __restrict__ VtG) {
    __shared__ u16 T[64 * 64];   // byte(r,c) = r*128 + ((c*2) ^ ((((r>>3)^r)&7)<<4))
    const int tb = blockIdx.x;   // token block (64 tokens)
    const int fb = blockIdx.y;   // feature block (64 feats)
    const int tid = threadIdx.x;
    char* Tb = (char*)T;
#pragma unroll
    for (int t = 0; t < 2; ++t) {
        int ci = t * 256 + tid;
        int r = ci >> 3, cb = ci & 7;
        s16x8 v = *(const s16x8*)(qkv + (size_t)(tb * 64 + r) * (3 * DMODEL) + 2 * DMODEL + fb * 64 + cb * 8);
        int kk = (((r >> 3) ^ r) & 7) << 4;
        *(s16x8*)(Tb + r * 128 + ((cb * 16) ^ kk)) = v;
    }
    __syncthreads();
#pragma unroll
    for (int t = 0; t < 2; ++t) {
        int co = t * 256 + tid;
        int f = co >> 3, t8 = co & 7;
        union { u16 us[8]; s16x8 v; } o;
#pragma unroll
        for (int x = 0; x < 8; ++x) {
            int r = t8 * 8 + x;
            int kk = (((r >> 3) ^ r) & 7) << 4;
            o.us[x] = *(const u16*)(Tb + r * 128 + ((f * 2) ^ kk));
        }
        *(s16x8*)(VtG + (size_t)(fb * 64 + f) * L_SEQ + tb * 64 + t8 * 8) = o.v;
    }
}

// ---------------- fused attention v5: R4 structure + deferred-max + l-via-MFMA ----------------
// grid (L/64, H), 4 waves x 16 q-rows. K and V^T staged via gld16 (swizzled,
// double-buffered, verified R4). Softmax: defer-max (THR=4 in log2 domain)
// removes the shfl max-reduce from the common path; denominator accumulated
// by MFMA against a ones matrix (no shfl sum-reduce at all).
__global__ __launch_bounds__(256, 2)
void k_attn(const u16* __restrict__ QKV, const u16* __restrict__ VtG,
            const float2* __restrict__ CSph,
            const float* __restrict__ gamma, u16* __restrict__ Oout) {
    const int h = blockIdx.y;
    const int qb = blockIdx.x * 64;
    const int tid = threadIdx.x;
    const int w = tid >> 6, lane = tid & 63;
    const int u = lane & 15, g = lane >> 4;
    const int ld = 3 * DMODEL;
    const int NT = L_SEQ / 64;
    const int BUF = 64 * 64 * 2;

    __shared__ u16 Ks[2][64 * 64];
    __shared__ u16 Vs[2][64 * 64];
    __shared__ u16 Pl[4][16 * 64];

    const float LOG2E = 1.44269504088896f;
    const float gate2 = (0.08f / (1.0f + __expf(-gamma[h]))) * LOG2E;
    const float SC2 = 0.125f * LOG2E;

    const u16* Qp = QKV + h * 64;
    const u16* Kp = QKV + DMODEL + h * 64;
    const u16* VtH = VtG + (size_t)h * 64 * L_SEQ;
    const float2* CS = CSph + (size_t)h * L_SEQ;

    s16x8 aq0, aq1;
    {
        const int qrow = qb + w * 16 + u;
        aq0 = *(const s16x8*)(Qp + (size_t)qrow * ld + g * 8);
        aq1 = *(const s16x8*)(Qp + (size_t)qrow * ld + 32 + g * 8);
    }
    float gcq[4], gsq[4];
#pragma unroll
    for (int r = 0; r < 4; ++r) {
        float2 cs = CS[qb + w * 16 + g * 4 + r];
        gcq[r] = gate2 * cs.x;
        gsq[r] = gate2 * cs.y;
    }

    // ones matrix fragment for the denominator MFMA
    union { u16 us[8]; s16x8 v; } one_;
#pragma unroll
    for (int i = 0; i < 8; ++i) one_.us[i] = 0x3F80;   // bf16 1.0
    const s16x8 vone = one_.v;

    // staging addresses: pre-swizzled global source, linear LDS dest (verified R4)
    unsigned dstOff[2];
    size_t srcK[2], srcV[2];
#pragma unroll
    for (int t = 0; t < 2; ++t) {
        int ci = (w * 2 + t) * 64 + lane;
        int row = ci >> 3, cb = ci & 7;
        dstOff[t] = (unsigned)((w * 2 + t) * 1024);
        srcK[t] = (size_t)row * ld + (size_t)((cb ^ (row & 7)) * 8);
        srcV[t] = (size_t)row * L_SEQ + (size_t)((cb ^ (row & 7)) * 8);
    }
    char* ksBase = (char*)Ks;
    char* vsBase = (char*)Vs;
    char* PlB = (char*)Pl + w * 2048;

    // prologue: stage tile 0 into buffer 0
#pragma unroll
    for (int t = 0; t < 2; ++t) {
        gld16(Kp + srcK[t], ksBase + dstOff[t]);
        gld16(VtH + srcV[t], vsBase + dstOff[t]);
    }
    __syncthreads();

    float mrow[4];
    f32x4 lacc = {};
    f32x4 oacc[4] = {};
#pragma unroll
    for (int r = 0; r < 4; ++r) mrow[r] = -1e30f;

    // phase features for tile 0 (prefetched; next-iter prefetch inside loop)
    float2 cskN[4];
#pragma unroll
    for (int kb = 0; kb < 4; ++kb) cskN[kb] = CS[kb * 16 + u];

    for (int kt = 0; kt < NT; ++kt) {
        const int cur = kt & 1;
        const char* kCur = ksBase + cur * BUF;
        const char* vCur = vsBase + cur * BUF;

        // V fragments from LDS, issued early (off the critical path)
        s16x8 vbr[4][2];
#pragma unroll
        for (int ks = 0; ks < 2; ++ks) {
            const int xv = (ks * 64 + g * 16) ^ ((u & 7) << 4);
#pragma unroll
            for (int db = 0; db < 4; ++db)
                vbr[db][ks] = *(const s16x8*)(vCur + (db * 16 + u) * 128 + xv);
        }

        // phase features: consume prefetched, prefetch next
        float ck4[4], sk4[4];
#pragma unroll
        for (int kb = 0; kb < 4; ++kb) { ck4[kb] = cskN[kb].x; sk4[kb] = cskN[kb].y; }
        if (kt + 1 < NT) {
#pragma unroll
            for (int kb = 0; kb < 4; ++kb)
                cskN[kb] = CS[(kt + 1) * 64 + kb * 16 + u];
        }

        // prefetch next K/V tile
        if (kt + 1 < NT) {
            const u16* Kn = Kp + (size_t)(kt + 1) * 64 * ld;
            const u16* Vn = VtH + (size_t)(kt + 1) * 64;
            char* kN = ksBase + (cur ^ 1) * BUF;
            char* vN = vsBase + (cur ^ 1) * BUF;
#pragma unroll
            for (int t = 0; t < 2; ++t) {
                gld16(Kn + srcK[t], kN + dstOff[t]);
                gld16(Vn + srcV[t], vN + dstOff[t]);
            }
        }

        // ---- S = Q K^T ----
        f32x4 sf[4] = {};
        const int x0 = (g * 16) ^ ((u & 7) << 4);
#pragma unroll
        for (int kb = 0; kb < 4; ++kb) {
            const int rowb = (kb * 16 + u) * 128;
            s16x8 b0 = *(const s16x8*)(kCur + rowb + x0);
            s16x8 b1 = *(const s16x8*)(kCur + rowb + (x0 ^ 64));
            sf[kb] = __builtin_amdgcn_mfma_f32_16x16x32_bf16(aq0, b0, sf[kb], 0, 0, 0);
            sf[kb] = __builtin_amdgcn_mfma_f32_16x16x32_bf16(aq1, b1, sf[kb], 0, 0, 0);
        }

        // ---- bias + lane-local max ----
        float sv[4][4], tmax[4];
#pragma unroll
        for (int r = 0; r < 4; ++r) tmax[r] = -1e30f;
#pragma unroll
        for (int kb = 0; kb < 4; ++kb)
#pragma unroll
            for (int r = 0; r < 4; ++r) {
                float xv = sf[kb][r] * SC2 + gcq[r] * ck4[kb] + gsq[r] * sk4[kb];
                sv[kb][r] = xv;
                tmax[r] = fmaxf(tmax[r], xv);
            }

        // ---- deferred max: only reduce + rescale when a lane exceeds m+THR ----
        bool need = false;
#pragma unroll
        for (int r = 0; r < 4; ++r) need |= (tmax[r] > mrow[r] + 4.0f);
        if (__any(need)) {
            float scl[4];
#pragma unroll
            for (int r = 0; r < 4; ++r) {
                float t = tmax[r];
#pragma unroll
                for (int msk = 1; msk <= 8; msk <<= 1)
                    t = fmaxf(t, __shfl_xor(t, msk));
                float mn = fmaxf(mrow[r], t);
                scl[r] = __builtin_amdgcn_exp2f(mrow[r] - mn);
                mrow[r] = mn;
            }
#pragma unroll
            for (int db = 0; db < 4; ++db)
#pragma unroll
                for (int r = 0; r < 4; ++r)
                    oacc[db][r] *= scl[r];
#pragma unroll
            for (int r = 0; r < 4; ++r) lacc[r] *= scl[r];
        }

        // ---- P = exp2(S - m) -> LDS (verified R4 layout) ----
#pragma unroll
        for (int kb = 0; kb < 4; ++kb)
#pragma unroll
            for (int r = 0; r < 4; ++r) {
                float p = __builtin_amdgcn_exp2f(sv[kb][r] - mrow[r]);
                int prow = g * 4 + r;
                int pb = prow * 128 + (kb * 16 + u) * 2;
                pb ^= (prow & 7) << 4;
                *(u16*)(PlB + pb) = f2b(p);
            }

        // ---- O += P V ; l += P * ones (denominator on the MFMA pipe) ----
#pragma unroll
        for (int ks = 0; ks < 2; ++ks) {
            s16x8 pa = *(const s16x8*)(PlB + u * 128 + ((ks * 64 + g * 16) ^ ((u & 7) << 4)));
            lacc = __builtin_amdgcn_mfma_f32_16x16x32_bf16(pa, vone, lacc, 0, 0, 0);
#pragma unroll
            for (int db = 0; db < 4; ++db)
                oacc[db] = __builtin_amdgcn_mfma_f32_16x16x32_bf16(pa, vbr[db][ks], oacc[db], 0, 0, 0);
        }
        __syncthreads();
    }

#pragma unroll
    for (int db = 0; db < 4; ++db)
#pragma unroll
        for (int r = 0; r < 4; ++r) {
            int qr = qb + w * 16 + g * 4 + r;
            int col = h * 64 + db * 16 + u;
            Oout[(size_t)qr * DMODEL + col] = f2b(oacc[db][r] / lacc[r]);
        }
}

extern "C" void kernel_launch(void* const* d_in, const int* in_sizes, int n_in,
                              void* d_out, int out_size, void* d_ws, size_t ws_size,
                              hipStream_t stream) {
    const float* x  = (const float*)d_in[0];
    const float* Wq = (const float*)d_in[1];
    const float* bq = (const float*)d_in[2];
    const float* Wk = (const float*)d_in[3];
    const float* bk = (const float*)d_in[4];
    const float* Wv = (const float*)d_in[5];
    const float* bv = (const float*)d_in[6];
    const float* Wo = (const float*)d_in[7];
    const float* bo = (const float*)d_in[8];
    const float* Wp = (const float*)d_in[9];
    const float* bp = (const float*)d_in[10];
    const float* gamma = (const float*)d_in[11];
    float* out = (float*)d_out;

    char* ws = (char*)d_ws;
    u16* xb = (u16*)ws;   ws += (size_t)L_SEQ * DMODEL * 2;
    u16* wqb = (u16*)ws;  ws += (size_t)DMODEL * DMODEL * 2;
    u16* wkb = (u16*)ws;  ws += (size_t)DMODEL * DMODEL * 2;
    u16* wvb = (u16*)ws;  ws += (size_t)DMODEL * DMODEL * 2;
    u16* wob = (u16*)ws;  ws += (size_t)DMODEL * DMODEL * 2;
    u16* qkv = (u16*)ws;  ws += (size_t)L_SEQ * 3 * DMODEL * 2;
    u16* attnb = (u16*)ws; ws += (size_t)L_SEQ * DMODEL * 2;
    u16* VtG = (u16*)ws;  ws += (size_t)DMODEL * L_SEQ * 2;
    float2* CSph = (float2*)ws; ws += (size_t)NHEAD * L_SEQ * 8;

    const int ntot8 = (L_SEQ * DMODEL + 4 * DMODEL * DMODEL) / 8;  // 786432
    k_tobf16_all<<<ntot8 / 256, 256, 0, stream>>>(x, Wq, Wk, Wv, Wo, xb, wqb, wkb, wvb, wob);

    k_phase<<<L_SEQ / 4, 256, 0, stream>>>(x, Wp, bp, CSph);

    // fused QKV projection -> qkv [2048, 3072] bf16
    k_gemm_bt<0><<<dim3(16, 24), 256, 0, stream>>>(xb, wqb, wkb, wvb, bq, bk, bv,
                                                   (void*)qkv, 3 * DMODEL, DMODEL);

    // V^T [1024, 2048] bf16
    k_transposeV<<<dim3(L_SEQ / 64, DMODEL / 64), 256, 0, stream>>>(qkv, VtG);

    k_attn<<<dim3(L_SEQ / 64, NHEAD), 256, 0, stream>>>(qkv, VtG, CSph, gamma, attnb);

    // output projection -> d_out f32 [2048, 1024]
    k_gemm_bt<1><<<dim3(16, 8), 256, 0, stream>>>(attnb, wob, wob, wob, bo, bo, bo,
                                                  (void*)out, DMODEL, DMODEL);
}